// Round 1
// baseline (1489.526 us; speedup 1.0000x reference)
//
#include <hip/hip_runtime.h>
#include <hip/hip_bf16.h>
#include <stdint.h>

#define HIDDEN 4096
#define NHEADS 32
#define HEADDIM 128
#define ROT 64
#define BB 2
#define SS 2048
#define NTOK (BB*SS)        // 4096 tokens
#define QKVN (3*HIDDEN)     // 12288

typedef __attribute__((ext_vector_type(8))) short short8;
typedef __attribute__((ext_vector_type(4))) float floatx4;

// ---------------- async global->LDS 16B (wave-uniform LDS base + lane*16) ----------------
__device__ __forceinline__ void async16(const __hip_bfloat16* g, unsigned lds_byte_addr) {
  __builtin_amdgcn_global_load_lds(
      (const __attribute__((address_space(1))) unsigned int*)(uintptr_t)g,
      (__attribute__((address_space(3))) unsigned int*)(uintptr_t)(uint64_t)lds_byte_addr,
      16, 0, 0);
}

// ---------------- cast fp32 -> bf16 ----------------
__global__ void cast_bf16_kernel(const float* __restrict__ x,
                                 __hip_bfloat16* __restrict__ y, int n4) {
  int idx = blockIdx.x * blockDim.x + threadIdx.x;
  if (idx >= n4) return;
  float4 v = ((const float4*)x)[idx];
  __hip_bfloat162 a, b;
  a.x = __float2bfloat16(v.x); a.y = __float2bfloat16(v.y);
  b.x = __float2bfloat16(v.z); b.y = __float2bfloat16(v.w);
  ((__hip_bfloat162*)y)[idx * 2]     = a;
  ((__hip_bfloat162*)y)[idx * 2 + 1] = b;
}

// ---------------- transpose+cast: Wt[n][k] (bf16) = W[k][n_off+n] (fp32, row stride ldn) ----
__global__ void transpose_cast_kernel(const float* __restrict__ W,
                                      __hip_bfloat16* __restrict__ Wt,
                                      int K, int ldn, int n_off) {
  int n  = blockIdx.x * 256 + threadIdx.x;
  int k0 = blockIdx.y * 32;
  const float* src = W + (size_t)k0 * ldn + n_off + n;
  short8 outv[4];
#pragma unroll
  for (int i = 0; i < 4; ++i) {
#pragma unroll
    for (int j = 0; j < 8; ++j) {
      __hip_bfloat16 b = __float2bfloat16(src[(size_t)(i * 8 + j) * ldn]);
      outv[i][j] = *reinterpret_cast<short*>(&b);
    }
  }
  __hip_bfloat16* dst = Wt + (size_t)n * K + k0;
#pragma unroll
  for (int i = 0; i < 4; ++i) *(short8*)(dst + i * 8) = outv[i];
}

// ---------------- m97-style MFMA GEMM: C[M,n0..] = A[M][K] * Bt[N][K]^T ----------------
// 128x128 tile, BK=32, global_load_lds width-16 staging, 4 waves x 64x64 quadrant.
// + bijective XCD-aware swizzle (T1): consecutive work tiles share A-panel per XCD L2.
__device__ inline void store_val(float* p, float v) { *p = v; }
__device__ inline void store_val(__hip_bfloat16* p, float v) { *p = __float2bfloat16(v); }

template <typename OutT>
__global__ __launch_bounds__(256) void gemm_bt_kernel(const __hip_bfloat16* __restrict__ A,
                                                      const __hip_bfloat16* __restrict__ Bt,
                                                      OutT* __restrict__ C,
                                                      int M, int K, int ldc) {
  __shared__ __hip_bfloat16 As[128 * 32];
  __shared__ __hip_bfloat16 Bs[128 * 32];
  const int tid  = threadIdx.x;
  const int wid  = tid >> 6;
  const int lane = tid & 63;
  const int quad = lane >> 4;
  const int l16  = lane & 15;
  const int wm   = (wid >> 1) * 64;
  const int wn   = (wid & 1) * 64;

  // XCD-aware swizzle (bijective when nwg % 8 == 0; all launches here satisfy this)
  const unsigned nwg = gridDim.x * gridDim.y;
  const unsigned wg  = blockIdx.y * gridDim.x + blockIdx.x;
  unsigned swz = wg;
  if ((nwg & 7u) == 0u) {
    const unsigned cpx = nwg >> 3;
    swz = (wg & 7u) * cpx + (wg >> 3);
  }
  const int m0 = (int)(swz / gridDim.x) * 128;
  const int n0 = (int)(swz % gridDim.x) * 128;

  const int srow = lane >> 2;        // lane i covers row i>>2 of its 16-row block
  const int scol = (lane & 3) * 8;   // and elems (i&3)*8 .. +7

  const unsigned as0 = (unsigned)(uintptr_t)(&As[0]);
  const unsigned bs0 = (unsigned)(uintptr_t)(&Bs[0]);

  floatx4 acc[4][4] = {};

  for (int kb = 0; kb < K; kb += 32) {
    __syncthreads();
#pragma unroll
    for (int j = 0; j < 2; ++j) {
      int rblk = wid * 32 + j * 16;
      unsigned la = __builtin_amdgcn_readfirstlane(as0 + rblk * 64);
      async16(A + (size_t)(m0 + rblk + srow) * K + kb + scol, la);
      unsigned lb = __builtin_amdgcn_readfirstlane(bs0 + rblk * 64);
      async16(Bt + (size_t)(n0 + rblk + srow) * K + kb + scol, lb);
    }
    __syncthreads();  // compiler emits s_waitcnt vmcnt(0) before barrier

    short8 af[4], bf[4];
#pragma unroll
    for (int t = 0; t < 4; ++t)
      af[t] = *(const short8*)(As + (wm + t * 16 + l16) * 32 + quad * 8);
#pragma unroll
    for (int t = 0; t < 4; ++t)
      bf[t] = *(const short8*)(Bs + (wn + t * 16 + l16) * 32 + quad * 8);
#pragma unroll
    for (int mi = 0; mi < 4; ++mi)
#pragma unroll
      for (int ni = 0; ni < 4; ++ni)
        acc[mi][ni] = __builtin_amdgcn_mfma_f32_16x16x32_bf16(af[mi], bf[ni], acc[mi][ni], 0, 0, 0);
  }

  // epilogue: C/D layout row=quad*4+r, col=lane&15 (verified m89/m91)
#pragma unroll
  for (int mi = 0; mi < 4; ++mi)
#pragma unroll
    for (int ni = 0; ni < 4; ++ni)
#pragma unroll
      for (int r = 0; r < 4; ++r) {
        int row = m0 + wm + mi * 16 + quad * 4 + r;
        int col = n0 + wn + ni * 16 + l16;
        store_val(C + (size_t)row * ldc + col, acc[mi][ni][r]);
      }
}

// ---------------- RoPE (NeoX), in place on q and k halves of qkv ----------------
__global__ void rope_kernel(__hip_bfloat16* __restrict__ qkv,
                            const int* __restrict__ positions) {
  int idx = blockIdx.x * blockDim.x + threadIdx.x;
  if (idx >= NTOK * NHEADS * (ROT / 2)) return;
  int i   = idx & 31;
  int h   = (idx >> 5) & 31;
  int tok = idx >> 10;
  float pos = (float)positions[tok];
  float inv_freq = __expf(-(float)i * 0.28782313662425574f);
  float ang = pos * inv_freq;
  float sv, cv;
  sincosf(ang, &sv, &cv);
  size_t base = (size_t)tok * QKVN + h * HEADDIM + i;
  {
    float x1 = __bfloat162float(qkv[base]);
    float x2 = __bfloat162float(qkv[base + 32]);
    qkv[base]      = __float2bfloat16(x1 * cv - x2 * sv);
    qkv[base + 32] = __float2bfloat16(x2 * cv + x1 * sv);
  }
  {
    float x1 = __bfloat162float(qkv[base + HIDDEN]);
    float x2 = __bfloat162float(qkv[base + HIDDEN + 32]);
    qkv[base + HIDDEN]      = __float2bfloat16(x1 * cv - x2 * sv);
    qkv[base + HIDDEN + 32] = __float2bfloat16(x2 * cv + x1 * sv);
  }
}

// ---------------- MFMA flash attention: QBLK=128, 8 waves, KVBLK=64 ----------------
// Per-tile staging (K restage + V transpose) amortized over 2x the MFMA work vs QBLK=64.
// Each wave owns 16 q-rows; per-wave compute path identical to the verified QBLK=64 version.
__global__ __launch_bounds__(512) void attn_kernel(const __hip_bfloat16* __restrict__ qkv,
                                                   __hip_bfloat16* __restrict__ out) {
  __shared__ __hip_bfloat16 QPs[128 * 136];   // Q tile; later aliased as P (stride 72)
  __shared__ __hip_bfloat16 Ks[64 * 136];
  __shared__ __hip_bfloat16 Vt[128 * 72];

  const int tid  = threadIdx.x;
  const int wid  = tid >> 6;          // 0..7
  const int lane = tid & 63;
  const int quad = lane >> 4;
  const int l16  = lane & 15;
  const int qt   = 15 - (blockIdx.x & 15);      // descending work: big blocks first
  const int h    = (blockIdx.x >> 4) & 31;
  const int b    = blockIdx.x >> 9;
  const int qtok0 = b * SS + qt * 128;
  const float scale = 0.08838834764831843f;

  // stage Q: 128 rows x 128 dims
#pragma unroll
  for (int i = 0; i < 4; ++i) {
    int c = tid + i * 512;
    int row = c >> 4;
    int dc  = (c & 15) * 8;
    short8 v = *(const short8*)(qkv + (size_t)(qtok0 + row) * QKVN + h * HEADDIM + dc);
    *(short8*)(QPs + row * 136 + dc) = v;
  }
  __syncthreads();
  short8 aq[4];
#pragma unroll
  for (int kc = 0; kc < 4; ++kc)
    aq[kc] = *(const short8*)(QPs + (wid * 16 + l16) * 136 + kc * 32 + quad * 8);

  float m_r[4], l_r[4];
  floatx4 accO[8];
#pragma unroll
  for (int r = 0; r < 4; ++r) { m_r[r] = -INFINITY; l_r[r] = 0.f; }
#pragma unroll
  for (int ni = 0; ni < 8; ++ni) accO[ni] = (floatx4){0.f, 0.f, 0.f, 0.f};

  __hip_bfloat16* Ps = QPs;

  const int ktmax = 2 * qt + 1;
  for (int kt = 0; kt <= ktmax; ++kt) {
    __syncthreads();
    const int ktok = b * SS + kt * 64;

    // stage K: 64 rows x 128 dims
#pragma unroll
    for (int i = 0; i < 2; ++i) {
      int c = tid + i * 512;
      int row = c >> 4;
      int dc  = (c & 15) * 8;
      short8 v = *(const short8*)(qkv + (size_t)(ktok + row) * QKVN + HIDDEN + h * HEADDIM + dc);
      *(short8*)(Ks + row * 136 + dc) = v;
    }
    // stage V transposed: Vt[d][k], 128 x 64 (stride 72)
#pragma unroll
    for (int i = 0; i < 4; ++i) {
      int c  = tid + i * 512;
      int dp = (c & 7) | ((c >> 3) & 0x38);
      int kp = ((c >> 3) & 7) | ((c >> 6) & 0x18);
      const __hip_bfloat16* g = qkv + (size_t)(ktok + 2 * kp) * QKVN + 2 * HIDDEN + h * HEADDIM + 2 * dp;
      __hip_bfloat162 v0 = *(const __hip_bfloat162*)g;
      __hip_bfloat162 v1 = *(const __hip_bfloat162*)(g + QKVN);
      __hip_bfloat162 w0, w1;
      w0.x = v0.x; w0.y = v1.x;
      w1.x = v0.y; w1.y = v1.y;
      *(__hip_bfloat162*)(Vt + (2 * dp) * 72 + 2 * kp)     = w0;
      *(__hip_bfloat162*)(Vt + (2 * dp + 1) * 72 + 2 * kp) = w1;
    }
    __syncthreads();

    // waves 0-3 (rows < 64) have an entirely-masked final tile: skip compute (wave-uniform)
    const bool active = !(wid < 4 && kt == ktmax);
    if (active) {
      floatx4 accS[4] = {};
#pragma unroll
      for (int ni = 0; ni < 4; ++ni)
#pragma unroll
        for (int kc = 0; kc < 4; ++kc) {
          short8 bk = *(const short8*)(Ks + (16 * ni + l16) * 136 + kc * 32 + quad * 8);
          accS[ni] = __builtin_amdgcn_mfma_f32_16x16x32_bf16(aq[kc], bk, accS[ni], 0, 0, 0);
        }

      float sv[4][4];
#pragma unroll
      for (int ni = 0; ni < 4; ++ni)
#pragma unroll
        for (int r = 0; r < 4; ++r) sv[ni][r] = accS[ni][r] * scale;
      if (kt >= 2 * qt) {   // diagonal zone: general causal mask
#pragma unroll
        for (int ni = 0; ni < 4; ++ni)
#pragma unroll
          for (int r = 0; r < 4; ++r)
            if (kt * 64 + 16 * ni + l16 > qt * 128 + wid * 16 + quad * 4 + r)
              sv[ni][r] = -INFINITY;
      }
#pragma unroll
      for (int r = 0; r < 4; ++r) {
        float mx = fmaxf(fmaxf(sv[0][r], sv[1][r]), fmaxf(sv[2][r], sv[3][r]));
        mx = fmaxf(mx, __shfl_xor(mx, 1));
        mx = fmaxf(mx, __shfl_xor(mx, 2));
        mx = fmaxf(mx, __shfl_xor(mx, 4));
        mx = fmaxf(mx, __shfl_xor(mx, 8));
        float mnew  = fmaxf(m_r[r], mx);
        float alpha = __expf(m_r[r] - mnew);
        float psum = 0.f;
#pragma unroll
        for (int ni = 0; ni < 4; ++ni) {
          float p = __expf(sv[ni][r] - mnew);
          psum += p;
          Ps[(wid * 16 + quad * 4 + r) * 72 + 16 * ni + l16] = __float2bfloat16(p);
        }
        psum += __shfl_xor(psum, 1);
        psum += __shfl_xor(psum, 2);
        psum += __shfl_xor(psum, 4);
        psum += __shfl_xor(psum, 8);
        l_r[r] = l_r[r] * alpha + psum;
        m_r[r] = mnew;
#pragma unroll
        for (int ni = 0; ni < 8; ++ni) accO[ni][r] *= alpha;
      }

      short8 ap[2];
#pragma unroll
      for (int kc = 0; kc < 2; ++kc)
        ap[kc] = *(const short8*)(Ps + (wid * 16 + l16) * 72 + kc * 32 + quad * 8);
#pragma unroll
      for (int ni = 0; ni < 8; ++ni)
#pragma unroll
        for (int kc = 0; kc < 2; ++kc) {
          short8 bv = *(const short8*)(Vt + (16 * ni + l16) * 72 + kc * 32 + quad * 8);
          accO[ni] = __builtin_amdgcn_mfma_f32_16x16x32_bf16(ap[kc], bv, accO[ni], 0, 0, 0);
        }
    }
  }

  float inv_l[4];
#pragma unroll
  for (int r = 0; r < 4; ++r) inv_l[r] = 1.0f / l_r[r];
#pragma unroll
  for (int ni = 0; ni < 8; ++ni)
#pragma unroll
    for (int r = 0; r < 4; ++r) {
      int row = qtok0 + wid * 16 + quad * 4 + r;
      int col = h * HEADDIM + 16 * ni + l16;
      out[(size_t)row * HIDDEN + col] = __float2bfloat16(accO[ni][r] * inv_l[r]);
    }
}

// ---------------- launch ----------------
extern "C" void kernel_launch(void* const* d_in, const int* in_sizes, int n_in,
                              void* d_out, int out_size, void* d_ws, size_t ws_size,
                              hipStream_t stream) {
  const float* hidden    = (const float*)d_in[0];
  const int*   positions = (const int*)d_in[1];
  const float* Wqkv      = (const float*)d_in[2];
  const float* Wout      = (const float*)d_in[3];
  float* out = (float*)d_out;

  const size_t R0_BYTES      = (size_t)NTOK * HIDDEN * 2;    // 33.55 MB: Xb, later Ab
  const size_t QKV_BYTES     = (size_t)NTOK * QKVN * 2;      // 100.66 MB
  const size_t WT_FULL_BYTES = (size_t)QKVN * HIDDEN * 2;    // 100.66 MB
  const size_t WT_CHUNK_BYTES= (size_t)HIDDEN * HIDDEN * 2;  // 33.55 MB

  const size_t WS_FULL  = R0_BYTES + WT_FULL_BYTES + QKV_BYTES;   // 234.9 MB
  const size_t WS_CHUNK = R0_BYTES + WT_CHUNK_BYTES + QKV_BYTES;  // 167.77 MB
  if (ws_size < WS_CHUNK) return;
  const bool full = (ws_size >= WS_FULL);

  char* ws = (char*)d_ws;
  __hip_bfloat16* Xb   = (__hip_bfloat16*)ws;                 // R0
  __hip_bfloat16* Ab   = (__hip_bfloat16*)ws;                 // R0 (aliases Xb, dead by then)
  __hip_bfloat16* Wt   = (__hip_bfloat16*)(ws + R0_BYTES);    // R1 (full or chunk)
  __hip_bfloat16* QKVb = (__hip_bfloat16*)(ws + R0_BYTES + (full ? WT_FULL_BYTES : WT_CHUNK_BYTES));

  // 1. cast hidden fp32 -> bf16
  cast_bf16_kernel<<<(NTOK * HIDDEN / 4 + 255) / 256, 256, 0, stream>>>(
      hidden, Xb, NTOK * HIDDEN / 4);

  // 2. QKV projection
  if (full) {
    transpose_cast_kernel<<<dim3(QKVN / 256, HIDDEN / 32), 256, 0, stream>>>(
        Wqkv, Wt, HIDDEN, QKVN, 0);
    gemm_bt_kernel<__hip_bfloat16><<<dim3(QKVN / 128, NTOK / 128), 256, 0, stream>>>(
        Xb, Wt, QKVb, NTOK, HIDDEN, QKVN);
  } else {
    for (int p = 0; p < 3; ++p) {
      transpose_cast_kernel<<<dim3(HIDDEN / 256, HIDDEN / 32), 256, 0, stream>>>(
          Wqkv, Wt, HIDDEN, QKVN, p * HIDDEN);
      gemm_bt_kernel<__hip_bfloat16><<<dim3(HIDDEN / 128, NTOK / 128), 256, 0, stream>>>(
          Xb, Wt, QKVb + p * HIDDEN, NTOK, HIDDEN, QKVN);
    }
  }

  // 3. RoPE on q,k
  rope_kernel<<<(NTOK * NHEADS * (ROT / 2) + 255) / 256, 256, 0, stream>>>(QKVb, positions);

  // 4. causal flash attention -> Ab (aliases Xb; Xb dead after gemm1)
  attn_kernel<<<BB * NHEADS * (SS / 128), 512, 0, stream>>>(QKVb, Ab);

  // 5. out projection (transpose Wout into Wt region — free after gemm1)
  transpose_cast_kernel<<<dim3(HIDDEN / 256, HIDDEN / 32), 256, 0, stream>>>(
      Wout, Wt, HIDDEN, HIDDEN, 0);
  gemm_bt_kernel<float><<<dim3(HIDDEN / 128, NTOK / 128), 256, 0, stream>>>(
      Ab, Wt, out, NTOK, HIDDEN, HIDDEN);
}

// Round 2
// 1255.693 us; speedup vs baseline: 1.1862x; 1.1862x over previous
//
#include <hip/hip_runtime.h>
#include <hip/hip_bf16.h>
#include <stdint.h>

#define HIDDEN 4096
#define NHEADS 32
#define HEADDIM 128
#define ROT 64
#define BB 2
#define SS 2048
#define NTOK (BB*SS)        // 4096 tokens
#define QKVN (3*HIDDEN)     // 12288

typedef __attribute__((ext_vector_type(8))) short short8;
typedef __attribute__((ext_vector_type(4))) float floatx4;

#define WAITV(N) asm volatile("s_waitcnt vmcnt(" #N ")" ::: "memory")

__device__ __forceinline__ void barrier_raw() {
  asm volatile("" ::: "memory");
  __builtin_amdgcn_s_barrier();
  asm volatile("" ::: "memory");
}

// ---------------- async global->LDS 16B (wave-uniform LDS base + lane*16) ----------------
__device__ __forceinline__ void async16(const __hip_bfloat16* g, unsigned lds_byte_addr) {
  __builtin_amdgcn_global_load_lds(
      (const __attribute__((address_space(1))) unsigned int*)(uintptr_t)g,
      (__attribute__((address_space(3))) unsigned int*)(uintptr_t)(uint64_t)lds_byte_addr,
      16, 0, 0);
}

// ---------------- cast fp32 -> bf16 ----------------
__global__ void cast_bf16_kernel(const float* __restrict__ x,
                                 __hip_bfloat16* __restrict__ y, int n4) {
  int idx = blockIdx.x * blockDim.x + threadIdx.x;
  if (idx >= n4) return;
  float4 v = ((const float4*)x)[idx];
  __hip_bfloat162 a, b;
  a.x = __float2bfloat16(v.x); a.y = __float2bfloat16(v.y);
  b.x = __float2bfloat16(v.z); b.y = __float2bfloat16(v.w);
  ((__hip_bfloat162*)y)[idx * 2]     = a;
  ((__hip_bfloat162*)y)[idx * 2 + 1] = b;
}

// ---------------- transpose+cast: Wt[n][k] (bf16) = W[k][n_off+n] (fp32, row stride ldn) ----
__global__ void transpose_cast_kernel(const float* __restrict__ W,
                                      __hip_bfloat16* __restrict__ Wt,
                                      int K, int ldn, int n_off) {
  int n  = blockIdx.x * 256 + threadIdx.x;
  int k0 = blockIdx.y * 32;
  const float* src = W + (size_t)k0 * ldn + n_off + n;
  short8 outv[4];
#pragma unroll
  for (int i = 0; i < 4; ++i) {
#pragma unroll
    for (int j = 0; j < 8; ++j) {
      __hip_bfloat16 b = __float2bfloat16(src[(size_t)(i * 8 + j) * ldn]);
      outv[i][j] = *reinterpret_cast<short*>(&b);
    }
  }
  __hip_bfloat16* dst = Wt + (size_t)n * K + k0;
#pragma unroll
  for (int i = 0; i < 4; ++i) *(short8*)(dst + i * 8) = outv[i];
}

// ---------------- 256x256-tile MFMA GEMM, BK=32, triple-buffered LDS, counted vmcnt ----
// C[M,n0..] = A[M][K] * Bt[N][K]^T.  8 waves (2Mx4N), each owns 128x64 output.
// Pipeline: stage tile t+2 while computing tile t; vmcnt(6) leaves 2 tiles in flight
// (T3+T4). T2 XOR slot-swizzle: linear global_load_lds dest + pre-swizzled global src
// + swizzled ds_read (both-sides rule). T5 setprio around MFMA clusters. T1 XCD swizzle.
__device__ inline void store_val(float* p, float v) { *p = v; }
__device__ inline void store_val(__hip_bfloat16* p, float v) { *p = __float2bfloat16(v); }

template <typename OutT>
__global__ __launch_bounds__(512) void gemm_bt256_kernel(const __hip_bfloat16* __restrict__ A,
                                                         const __hip_bfloat16* __restrict__ Bt,
                                                         OutT* __restrict__ C,
                                                         int M, int K, int ldc) {
  // 3 buffers x (256 rows x 32 bf16) per operand = 96 KB total
  __shared__ __align__(16) __hip_bfloat16 As[3 * 8192];
  __shared__ __align__(16) __hip_bfloat16 Bs[3 * 8192];

  const int tid  = threadIdx.x;
  const int wid  = tid >> 6;           // 0..7
  const int lane = tid & 63;
  const int quad = lane >> 4;
  const int l16  = lane & 15;
  const int wm   = (wid >> 2) * 128;   // wave row offset
  const int wn   = (wid & 3) * 64;     // wave col offset

  // XCD-aware bijective swizzle (all launches have nwg % 8 == 0)
  const unsigned nwg = gridDim.x * gridDim.y;
  const unsigned wg  = blockIdx.y * gridDim.x + blockIdx.x;
  unsigned swz = wg;
  if ((nwg & 7u) == 0u) swz = (wg & 7u) * (nwg >> 3) + (wg >> 3);
  const int m0 = (int)(swz / gridDim.x) * 256;
  const int n0 = (int)(swz % gridDim.x) * 256;

  // staging geometry: call j covers rows j*128 + wid*16 + (lane>>2), 16B slot lane&3.
  // T2 swizzle: phys slot s holds logical slot s ^ swz(row); swz(row)=(row&3)^((row>>2)&3).
  const int srow = lane >> 2;
  const int sg8  = (((lane & 3) ^ ((lane >> 2) & 3) ^ ((lane >> 4) & 3))) * 8; // global slot
  const int sq8  = ((quad ^ (l16 & 3) ^ (l16 >> 2))) * 8;                      // read slot

  const unsigned asB = (unsigned)(uintptr_t)(&As[0]);
  const unsigned bsB = (unsigned)(uintptr_t)(&Bs[0]);

  const __hip_bfloat16* pA = A  + (size_t)(m0 + wid * 16 + srow) * K + sg8;
  const __hip_bfloat16* pB = Bt + (size_t)(n0 + wid * 16 + srow) * K + sg8;
  const size_t rowskip = (size_t)128 * K;

  auto stageA = [&](int tile, int kb) {
    unsigned base = asB + (unsigned)((tile % 3) * 16384) + (unsigned)(wid * 1024);
    async16(pA + kb,           __builtin_amdgcn_readfirstlane(base));
    async16(pA + rowskip + kb, __builtin_amdgcn_readfirstlane(base + 8192));
  };
  auto stageB = [&](int tile, int kb) {
    unsigned base = bsB + (unsigned)((tile % 3) * 16384) + (unsigned)(wid * 1024);
    async16(pB + kb,           __builtin_amdgcn_readfirstlane(base));
    async16(pB + rowskip + kb, __builtin_amdgcn_readfirstlane(base + 8192));
  };

  const int NT = K >> 5;   // K/32 tiles (K=4096 -> 128)
  floatx4 acc[8][4] = {};

  // prologue: tiles 0 and 1 in flight (8 loads)
  stageA(0, 0);  stageB(0, 0);
  stageA(1, 32); stageB(1, 32);

  for (int t = 0; t < NT; ++t) {
    const int bufO = (t % 3) * 8192;

    if (t + 2 < NT) stageA(t + 2, (t + 2) * 32);

    // drain exactly tile t's 4 loads; keep later tiles in flight across the barrier
    if (t + 2 < NT)      WAITV(6);
    else if (t + 1 < NT) WAITV(4);
    else                 WAITV(0);
    barrier_raw();

    short8 af[8], bf[4];
#pragma unroll
    for (int x = 0; x < 8; ++x)
      af[x] = *(const short8*)(As + bufO + (wm + x * 16 + l16) * 32 + sq8);
#pragma unroll
    for (int x = 0; x < 4; ++x)
      bf[x] = *(const short8*)(Bs + bufO + (wn + x * 16 + l16) * 32 + sq8);

    __builtin_amdgcn_s_setprio(1);
#pragma unroll
    for (int mi = 0; mi < 4; ++mi)
#pragma unroll
      for (int ni = 0; ni < 4; ++ni)
        acc[mi][ni] = __builtin_amdgcn_mfma_f32_16x16x32_bf16(af[mi], bf[ni], acc[mi][ni], 0, 0, 0);
    __builtin_amdgcn_s_setprio(0);

    if (t + 2 < NT) stageB(t + 2, (t + 2) * 32);

    __builtin_amdgcn_s_setprio(1);
#pragma unroll
    for (int mi = 4; mi < 8; ++mi)
#pragma unroll
      for (int ni = 0; ni < 4; ++ni)
        acc[mi][ni] = __builtin_amdgcn_mfma_f32_16x16x32_bf16(af[mi], bf[ni], acc[mi][ni], 0, 0, 0);
    __builtin_amdgcn_s_setprio(0);

    barrier_raw();
  }

  // epilogue: C/D layout row=quad*4+r, col=lane&15 (verified m89/m91)
#pragma unroll
  for (int mi = 0; mi < 8; ++mi)
#pragma unroll
    for (int ni = 0; ni < 4; ++ni)
#pragma unroll
      for (int r = 0; r < 4; ++r) {
        int row = m0 + wm + mi * 16 + quad * 4 + r;
        int col = n0 + wn + ni * 16 + l16;
        store_val(C + (size_t)row * ldc + col, acc[mi][ni][r]);
      }
}

// ---------------- RoPE (NeoX), in place on q and k halves of qkv ----------------
__global__ void rope_kernel(__hip_bfloat16* __restrict__ qkv,
                            const int* __restrict__ positions) {
  int idx = blockIdx.x * blockDim.x + threadIdx.x;
  if (idx >= NTOK * NHEADS * (ROT / 2)) return;
  int i   = idx & 31;
  int h   = (idx >> 5) & 31;
  int tok = idx >> 10;
  float pos = (float)positions[tok];
  float inv_freq = __expf(-(float)i * 0.28782313662425574f);
  float ang = pos * inv_freq;
  float sv, cv;
  sincosf(ang, &sv, &cv);
  size_t base = (size_t)tok * QKVN + h * HEADDIM + i;
  {
    float x1 = __bfloat162float(qkv[base]);
    float x2 = __bfloat162float(qkv[base + 32]);
    qkv[base]      = __float2bfloat16(x1 * cv - x2 * sv);
    qkv[base + 32] = __float2bfloat16(x2 * cv + x1 * sv);
  }
  {
    float x1 = __bfloat162float(qkv[base + HIDDEN]);
    float x2 = __bfloat162float(qkv[base + HIDDEN + 32]);
    qkv[base + HIDDEN]      = __float2bfloat16(x1 * cv - x2 * sv);
    qkv[base + HIDDEN + 32] = __float2bfloat16(x2 * cv + x1 * sv);
  }
}

// ---------------- MFMA flash attention: QBLK=128, 8 waves, KVBLK=64 ----------------
__global__ __launch_bounds__(512) void attn_kernel(const __hip_bfloat16* __restrict__ qkv,
                                                   __hip_bfloat16* __restrict__ out) {
  __shared__ __hip_bfloat16 QPs[128 * 136];   // Q tile; later aliased as P (stride 72)
  __shared__ __hip_bfloat16 Ks[64 * 136];
  __shared__ __hip_bfloat16 Vt[128 * 72];

  const int tid  = threadIdx.x;
  const int wid  = tid >> 6;          // 0..7
  const int lane = tid & 63;
  const int quad = lane >> 4;
  const int l16  = lane & 15;
  const int qt   = 15 - (blockIdx.x & 15);      // descending work: big blocks first
  const int h    = (blockIdx.x >> 4) & 31;
  const int b    = blockIdx.x >> 9;
  const int qtok0 = b * SS + qt * 128;
  const float scale = 0.08838834764831843f;

  // stage Q: 128 rows x 128 dims
#pragma unroll
  for (int i = 0; i < 4; ++i) {
    int c = tid + i * 512;
    int row = c >> 4;
    int dc  = (c & 15) * 8;
    short8 v = *(const short8*)(qkv + (size_t)(qtok0 + row) * QKVN + h * HEADDIM + dc);
    *(short8*)(QPs + row * 136 + dc) = v;
  }
  __syncthreads();
  short8 aq[4];
#pragma unroll
  for (int kc = 0; kc < 4; ++kc)
    aq[kc] = *(const short8*)(QPs + (wid * 16 + l16) * 136 + kc * 32 + quad * 8);

  float m_r[4], l_r[4];
  floatx4 accO[8];
#pragma unroll
  for (int r = 0; r < 4; ++r) { m_r[r] = -INFINITY; l_r[r] = 0.f; }
#pragma unroll
  for (int ni = 0; ni < 8; ++ni) accO[ni] = (floatx4){0.f, 0.f, 0.f, 0.f};

  __hip_bfloat16* Ps = QPs;

  const int ktmax = 2 * qt + 1;
  for (int kt = 0; kt <= ktmax; ++kt) {
    __syncthreads();
    const int ktok = b * SS + kt * 64;

    // stage K: 64 rows x 128 dims
#pragma unroll
    for (int i = 0; i < 2; ++i) {
      int c = tid + i * 512;
      int row = c >> 4;
      int dc  = (c & 15) * 8;
      short8 v = *(const short8*)(qkv + (size_t)(ktok + row) * QKVN + HIDDEN + h * HEADDIM + dc);
      *(short8*)(Ks + row * 136 + dc) = v;
    }
    // stage V transposed: Vt[d][k], 128 x 64 (stride 72)
#pragma unroll
    for (int i = 0; i < 4; ++i) {
      int c  = tid + i * 512;
      int dp = (c & 7) | ((c >> 3) & 0x38);
      int kp = ((c >> 3) & 7) | ((c >> 6) & 0x18);
      const __hip_bfloat16* g = qkv + (size_t)(ktok + 2 * kp) * QKVN + 2 * HIDDEN + h * HEADDIM + 2 * dp;
      __hip_bfloat162 v0 = *(const __hip_bfloat162*)g;
      __hip_bfloat162 v1 = *(const __hip_bfloat162*)(g + QKVN);
      __hip_bfloat162 w0, w1;
      w0.x = v0.x; w0.y = v1.x;
      w1.x = v0.y; w1.y = v1.y;
      *(__hip_bfloat162*)(Vt + (2 * dp) * 72 + 2 * kp)     = w0;
      *(__hip_bfloat162*)(Vt + (2 * dp + 1) * 72 + 2 * kp) = w1;
    }
    __syncthreads();

    // waves 0-3 (rows < 64) have an entirely-masked final tile: skip compute (wave-uniform)
    const bool active = !(wid < 4 && kt == ktmax);
    if (active) {
      floatx4 accS[4] = {};
#pragma unroll
      for (int ni = 0; ni < 4; ++ni)
#pragma unroll
        for (int kc = 0; kc < 4; ++kc) {
          short8 bk = *(const short8*)(Ks + (16 * ni + l16) * 136 + kc * 32 + quad * 8);
          accS[ni] = __builtin_amdgcn_mfma_f32_16x16x32_bf16(aq[kc], bk, accS[ni], 0, 0, 0);
        }

      float sv[4][4];
#pragma unroll
      for (int ni = 0; ni < 4; ++ni)
#pragma unroll
        for (int r = 0; r < 4; ++r) sv[ni][r] = accS[ni][r] * scale;
      if (kt >= 2 * qt) {   // diagonal zone: general causal mask
#pragma unroll
        for (int ni = 0; ni < 4; ++ni)
#pragma unroll
          for (int r = 0; r < 4; ++r)
            if (kt * 64 + 16 * ni + l16 > qt * 128 + wid * 16 + quad * 4 + r)
              sv[ni][r] = -INFINITY;
      }
#pragma unroll
      for (int r = 0; r < 4; ++r) {
        float mx = fmaxf(fmaxf(sv[0][r], sv[1][r]), fmaxf(sv[2][r], sv[3][r]));
        mx = fmaxf(mx, __shfl_xor(mx, 1));
        mx = fmaxf(mx, __shfl_xor(mx, 2));
        mx = fmaxf(mx, __shfl_xor(mx, 4));
        mx = fmaxf(mx, __shfl_xor(mx, 8));
        float mnew  = fmaxf(m_r[r], mx);
        float alpha = __expf(m_r[r] - mnew);
        float psum = 0.f;
#pragma unroll
        for (int ni = 0; ni < 4; ++ni) {
          float p = __expf(sv[ni][r] - mnew);
          psum += p;
          Ps[(wid * 16 + quad * 4 + r) * 72 + 16 * ni + l16] = __float2bfloat16(p);
        }
        psum += __shfl_xor(psum, 1);
        psum += __shfl_xor(psum, 2);
        psum += __shfl_xor(psum, 4);
        psum += __shfl_xor(psum, 8);
        l_r[r] = l_r[r] * alpha + psum;
        m_r[r] = mnew;
#pragma unroll
        for (int ni = 0; ni < 8; ++ni) accO[ni][r] *= alpha;
      }

      short8 ap[2];
#pragma unroll
      for (int kc = 0; kc < 2; ++kc)
        ap[kc] = *(const short8*)(Ps + (wid * 16 + l16) * 72 + kc * 32 + quad * 8);
#pragma unroll
      for (int ni = 0; ni < 8; ++ni)
#pragma unroll
        for (int kc = 0; kc < 2; ++kc) {
          short8 bv = *(const short8*)(Vt + (16 * ni + l16) * 72 + kc * 32 + quad * 8);
          accO[ni] = __builtin_amdgcn_mfma_f32_16x16x32_bf16(ap[kc], bv, accO[ni], 0, 0, 0);
        }
    }
  }

  float inv_l[4];
#pragma unroll
  for (int r = 0; r < 4; ++r) inv_l[r] = 1.0f / l_r[r];
#pragma unroll
  for (int ni = 0; ni < 8; ++ni)
#pragma unroll
    for (int r = 0; r < 4; ++r) {
      int row = qtok0 + wid * 16 + quad * 4 + r;
      int col = h * HEADDIM + 16 * ni + l16;
      out[(size_t)row * HIDDEN + col] = __float2bfloat16(accO[ni][r] * inv_l[r]);
    }
}

// ---------------- launch ----------------
extern "C" void kernel_launch(void* const* d_in, const int* in_sizes, int n_in,
                              void* d_out, int out_size, void* d_ws, size_t ws_size,
                              hipStream_t stream) {
  const float* hidden    = (const float*)d_in[0];
  const int*   positions = (const int*)d_in[1];
  const float* Wqkv      = (const float*)d_in[2];
  const float* Wout      = (const float*)d_in[3];
  float* out = (float*)d_out;

  const size_t R0_BYTES      = (size_t)NTOK * HIDDEN * 2;    // 33.55 MB: Xb, later Ab
  const size_t QKV_BYTES     = (size_t)NTOK * QKVN * 2;      // 100.66 MB
  const size_t WT_FULL_BYTES = (size_t)QKVN * HIDDEN * 2;    // 100.66 MB
  const size_t WT_CHUNK_BYTES= (size_t)HIDDEN * HIDDEN * 2;  // 33.55 MB

  const size_t WS_FULL  = R0_BYTES + WT_FULL_BYTES + QKV_BYTES;   // 234.9 MB
  const size_t WS_CHUNK = R0_BYTES + WT_CHUNK_BYTES + QKV_BYTES;  // 167.77 MB
  if (ws_size < WS_CHUNK) return;
  const bool full = (ws_size >= WS_FULL);

  char* ws = (char*)d_ws;
  __hip_bfloat16* Xb   = (__hip_bfloat16*)ws;                 // R0
  __hip_bfloat16* Ab   = (__hip_bfloat16*)ws;                 // R0 (aliases Xb, dead by then)
  __hip_bfloat16* Wt   = (__hip_bfloat16*)(ws + R0_BYTES);    // R1 (full or chunk)
  __hip_bfloat16* QKVb = (__hip_bfloat16*)(ws + R0_BYTES + (full ? WT_FULL_BYTES : WT_CHUNK_BYTES));

  // 1. cast hidden fp32 -> bf16
  cast_bf16_kernel<<<(NTOK * HIDDEN / 4 + 255) / 256, 256, 0, stream>>>(
      hidden, Xb, NTOK * HIDDEN / 4);

  // 2. QKV projection
  if (full) {
    transpose_cast_kernel<<<dim3(QKVN / 256, HIDDEN / 32), 256, 0, stream>>>(
        Wqkv, Wt, HIDDEN, QKVN, 0);
    gemm_bt256_kernel<__hip_bfloat16><<<dim3(QKVN / 256, NTOK / 256), 512, 0, stream>>>(
        Xb, Wt, QKVb, NTOK, HIDDEN, QKVN);
  } else {
    for (int p = 0; p < 3; ++p) {
      transpose_cast_kernel<<<dim3(HIDDEN / 256, HIDDEN / 32), 256, 0, stream>>>(
          Wqkv, Wt, HIDDEN, QKVN, p * HIDDEN);
      gemm_bt256_kernel<__hip_bfloat16><<<dim3(HIDDEN / 256, NTOK / 256), 512, 0, stream>>>(
          Xb, Wt, QKVb + p * HIDDEN, NTOK, HIDDEN, QKVN);
    }
  }

  // 3. RoPE on q,k
  rope_kernel<<<(NTOK * NHEADS * (ROT / 2) + 255) / 256, 256, 0, stream>>>(QKVb, positions);

  // 4. causal flash attention -> Ab (aliases Xb; Xb dead after gemm1)
  attn_kernel<<<BB * NHEADS * (SS / 128), 512, 0, stream>>>(QKVb, Ab);

  // 5. out projection (transpose Wout into Wt region — free after gemm1)
  transpose_cast_kernel<<<dim3(HIDDEN / 256, HIDDEN / 32), 256, 0, stream>>>(
      Wout, Wt, HIDDEN, HIDDEN, 0);
  gemm_bt256_kernel<float><<<dim3(HIDDEN / 256, NTOK / 256), 512, 0, stream>>>(
      Ab, Wt, out, NTOK, HIDDEN, HIDDEN);
}

// Round 3
// 1235.508 us; speedup vs baseline: 1.2056x; 1.0163x over previous
//
#include <hip/hip_runtime.h>
#include <hip/hip_bf16.h>
#include <stdint.h>

#define HIDDEN 4096
#define NHEADS 32
#define HEADDIM 128
#define ROT 64
#define BB 2
#define SS 2048
#define NTOK (BB*SS)        // 4096 tokens
#define QKVN (3*HIDDEN)     // 12288

typedef __attribute__((ext_vector_type(8))) short short8;
typedef __attribute__((ext_vector_type(4))) float floatx4;

#define WAITV(N) asm volatile("s_waitcnt vmcnt(" #N ")" ::: "memory")

__device__ __forceinline__ void barrier_raw() {
  asm volatile("" ::: "memory");
  __builtin_amdgcn_s_barrier();
  asm volatile("" ::: "memory");
}

// ---------------- async global->LDS 16B (wave-uniform LDS base + lane*16) ----------------
__device__ __forceinline__ void async16(const __hip_bfloat16* g, unsigned lds_byte_addr) {
  __builtin_amdgcn_global_load_lds(
      (const __attribute__((address_space(1))) unsigned int*)(uintptr_t)g,
      (__attribute__((address_space(3))) unsigned int*)(uintptr_t)(uint64_t)lds_byte_addr,
      16, 0, 0);
}

// ---------------- cast fp32 -> bf16 ----------------
__global__ void cast_bf16_kernel(const float* __restrict__ x,
                                 __hip_bfloat16* __restrict__ y, int n4) {
  int idx = blockIdx.x * blockDim.x + threadIdx.x;
  if (idx >= n4) return;
  float4 v = ((const float4*)x)[idx];
  __hip_bfloat162 a, b;
  a.x = __float2bfloat16(v.x); a.y = __float2bfloat16(v.y);
  b.x = __float2bfloat16(v.z); b.y = __float2bfloat16(v.w);
  ((__hip_bfloat162*)y)[idx * 2]     = a;
  ((__hip_bfloat162*)y)[idx * 2 + 1] = b;
}

// ---------------- transpose+cast: Wt[n][k] (bf16) = W[k][n_off+n] (fp32, row stride ldn) ----
__global__ void transpose_cast_kernel(const float* __restrict__ W,
                                      __hip_bfloat16* __restrict__ Wt,
                                      int K, int ldn, int n_off) {
  int n  = blockIdx.x * 256 + threadIdx.x;
  int k0 = blockIdx.y * 32;
  const float* src = W + (size_t)k0 * ldn + n_off + n;
  short8 outv[4];
#pragma unroll
  for (int i = 0; i < 4; ++i) {
#pragma unroll
    for (int j = 0; j < 8; ++j) {
      __hip_bfloat16 b = __float2bfloat16(src[(size_t)(i * 8 + j) * ldn]);
      outv[i][j] = *reinterpret_cast<short*>(&b);
    }
  }
  __hip_bfloat16* dst = Wt + (size_t)n * K + k0;
#pragma unroll
  for (int i = 0; i < 4; ++i) *(short8*)(dst + i * 8) = outv[i];
}

// ---------------- 256x256-tile MFMA GEMM, BK=64, k-half phased pipeline ----------------
// C[M,n0..] = A[M][K] * Bt[N][K]^T.  8 waves (2Mx4N), per-wave 128x64 output.
// LDS: 2 buffers x 2 k-halves x 256 rows x 32 bf16 per operand = 128 KB.
// Schedule (T3+T4): 2 phases per K-tile (one per k-half). Each phase:
//   issue 4 staging loads (same k-half, tile t+1) -> vmcnt(8) [drains exactly the
//   k-half consumed now, leaves 2 half-chunks in flight] -> s_barrier ->
//   12 ds_read_b128 -> setprio(1) 32 MFMA setprio(0).
// Staging order == consumption order (A-k0,B-k0 | A-k1,B-k1), so vmcnt never
// drains to 0 inside the loop. One barrier per phase (WAR distance = 2 barriers).
__device__ inline void store_val(float* p, float v) { *p = v; }
__device__ inline void store_val(__hip_bfloat16* p, float v) { *p = __float2bfloat16(v); }

template <typename OutT>
__global__ __launch_bounds__(512) void gemm_bt256_kernel(const __hip_bfloat16* __restrict__ A,
                                                         const __hip_bfloat16* __restrict__ Bt,
                                                         OutT* __restrict__ C,
                                                         int M, int K, int ldc) {
  // [buf][khalf][row 256][32 bf16]  -> 2*2*256*32 = 32768 elems = 64 KB each
  __shared__ __align__(16) __hip_bfloat16 As[32768];
  __shared__ __align__(16) __hip_bfloat16 Bs[32768];

  const int tid  = threadIdx.x;
  const int wid  = tid >> 6;           // 0..7
  const int lane = tid & 63;
  const int quad = lane >> 4;
  const int l16  = lane & 15;
  const int wm   = (wid >> 2) * 128;   // wave row offset (2 M-halves)
  const int wn   = (wid & 3) * 64;     // wave col offset (4 N-quarters)

  // XCD-aware bijective swizzle (all launches have nwg % 8 == 0)
  const unsigned nwg = gridDim.x * gridDim.y;
  const unsigned wg  = blockIdx.y * gridDim.x + blockIdx.x;
  unsigned swz = wg;
  if ((nwg & 7u) == 0u) swz = (wg & 7u) * (nwg >> 3) + (wg >> 3);
  const int m0 = (int)(swz / gridDim.x) * 256;
  const int n0 = (int)(swz % gridDim.x) * 256;

  // staging: thread covers rows (wid*16 + (lane>>2)) and +128; 16B slot lane&3.
  // slot-swizzle pair (R2-verified): global src slot sg8 <-> LDS read slot sq8.
  const int srow = lane >> 2;
  const int sg8  = (((lane & 3) ^ ((lane >> 2) & 3) ^ ((lane >> 4) & 3))) * 8;
  const int sq8  = ((quad ^ (l16 & 3) ^ (l16 >> 2))) * 8;

  const unsigned asB = (unsigned)(uintptr_t)(&As[0]);
  const unsigned bsB = (unsigned)(uintptr_t)(&Bs[0]);

  const __hip_bfloat16* pA = A  + (size_t)(m0 + wid * 16 + srow) * K + sg8;
  const __hip_bfloat16* pB = Bt + (size_t)(n0 + wid * 16 + srow) * K + sg8;
  const size_t rowskip = (size_t)128 * K;

  // stage one (operand-pair, k-half) chunk of K-tile `tile` into buf tile&1:
  // 4 loads: A rows 0-127, A rows 128-255? -> per call: A 2 loads + B 2 loads.
  auto stage = [&](int tile, int ks) {
    const int col = tile * 64 + ks * 32;
    unsigned rb = (unsigned)((tile & 1) * 32768 + ks * 16384 + wid * 1024);
    unsigned la = __builtin_amdgcn_readfirstlane(asB + rb);
    async16(pA + col,           la);
    async16(pA + rowskip + col, la + 8192);
    unsigned lb = __builtin_amdgcn_readfirstlane(bsB + rb);
    async16(pB + col,           lb);
    async16(pB + rowskip + col, lb + 8192);
  };

  const int NT = K >> 6;   // K/64 tiles (K=4096 -> 64)
  floatx4 acc[8][4] = {};

  // prologue: tile 0 fully in flight (both k-halves, 8 loads)
  stage(0, 0);
  stage(0, 1);

  for (int t = 0; t < NT; ++t) {
    const int bufE = (t & 1) * 16384;   // elem offset of this tile's buffer
#pragma unroll
    for (int ks = 0; ks < 2; ++ks) {
      if (t + 1 < NT) stage(t + 1, ks);

      // drain exactly the (t, ks) chunk; keep later chunks in flight
      if (t + 1 < NT)      WAITV(8);
      else if (ks == 0)    WAITV(4);
      else                 WAITV(0);
      barrier_raw();

      const int rgE = bufE + ks * 8192;   // region elem offset
      short8 af[8], bf[4];
#pragma unroll
      for (int x = 0; x < 8; ++x)
        af[x] = *(const short8*)(As + rgE + (wm + x * 16 + l16) * 32 + sq8);
#pragma unroll
      for (int x = 0; x < 4; ++x)
        bf[x] = *(const short8*)(Bs + rgE + (wn + x * 16 + l16) * 32 + sq8);

      __builtin_amdgcn_s_setprio(1);
#pragma unroll
      for (int mi = 0; mi < 8; ++mi)
#pragma unroll
        for (int ni = 0; ni < 4; ++ni)
          acc[mi][ni] = __builtin_amdgcn_mfma_f32_16x16x32_bf16(af[mi], bf[ni], acc[mi][ni], 0, 0, 0);
      __builtin_amdgcn_s_setprio(0);
    }
  }

  // epilogue: C/D layout row=quad*4+r, col=lane&15 (verified m89/m91)
#pragma unroll
  for (int mi = 0; mi < 8; ++mi)
#pragma unroll
    for (int ni = 0; ni < 4; ++ni)
#pragma unroll
      for (int r = 0; r < 4; ++r) {
        int row = m0 + wm + mi * 16 + quad * 4 + r;
        int col = n0 + wn + ni * 16 + l16;
        store_val(C + (size_t)row * ldc + col, acc[mi][ni][r]);
      }
}

// ---------------- RoPE (NeoX), in place on q and k halves of qkv ----------------
__global__ void rope_kernel(__hip_bfloat16* __restrict__ qkv,
                            const int* __restrict__ positions) {
  int idx = blockIdx.x * blockDim.x + threadIdx.x;
  if (idx >= NTOK * NHEADS * (ROT / 2)) return;
  int i   = idx & 31;
  int h   = (idx >> 5) & 31;
  int tok = idx >> 10;
  float pos = (float)positions[tok];
  float inv_freq = __expf(-(float)i * 0.28782313662425574f);
  float ang = pos * inv_freq;
  float sv, cv;
  sincosf(ang, &sv, &cv);
  size_t base = (size_t)tok * QKVN + h * HEADDIM + i;
  {
    float x1 = __bfloat162float(qkv[base]);
    float x2 = __bfloat162float(qkv[base + 32]);
    qkv[base]      = __float2bfloat16(x1 * cv - x2 * sv);
    qkv[base + 32] = __float2bfloat16(x2 * cv + x1 * sv);
  }
  {
    float x1 = __bfloat162float(qkv[base + HIDDEN]);
    float x2 = __bfloat162float(qkv[base + HIDDEN + 32]);
    qkv[base + HIDDEN]      = __float2bfloat16(x1 * cv - x2 * sv);
    qkv[base + HIDDEN + 32] = __float2bfloat16(x2 * cv + x1 * sv);
  }
}

// ---------------- MFMA flash attention: QBLK=128, 8 waves, KVBLK=64 ----------------
__global__ __launch_bounds__(512) void attn_kernel(const __hip_bfloat16* __restrict__ qkv,
                                                   __hip_bfloat16* __restrict__ out) {
  __shared__ __hip_bfloat16 QPs[128 * 136];   // Q tile; later aliased as P (stride 72)
  __shared__ __hip_bfloat16 Ks[64 * 136];
  __shared__ __hip_bfloat16 Vt[128 * 72];

  const int tid  = threadIdx.x;
  const int wid  = tid >> 6;          // 0..7
  const int lane = tid & 63;
  const int quad = lane >> 4;
  const int l16  = lane & 15;
  const int qt   = 15 - (blockIdx.x & 15);      // descending work: big blocks first
  const int h    = (blockIdx.x >> 4) & 31;
  const int b    = blockIdx.x >> 9;
  const int qtok0 = b * SS + qt * 128;
  const float scale = 0.08838834764831843f;

  // stage Q: 128 rows x 128 dims
#pragma unroll
  for (int i = 0; i < 4; ++i) {
    int c = tid + i * 512;
    int row = c >> 4;
    int dc  = (c & 15) * 8;
    short8 v = *(const short8*)(qkv + (size_t)(qtok0 + row) * QKVN + h * HEADDIM + dc);
    *(short8*)(QPs + row * 136 + dc) = v;
  }
  __syncthreads();
  short8 aq[4];
#pragma unroll
  for (int kc = 0; kc < 4; ++kc)
    aq[kc] = *(const short8*)(QPs + (wid * 16 + l16) * 136 + kc * 32 + quad * 8);

  float m_r[4], l_r[4];
  floatx4 accO[8];
#pragma unroll
  for (int r = 0; r < 4; ++r) { m_r[r] = -INFINITY; l_r[r] = 0.f; }
#pragma unroll
  for (int ni = 0; ni < 8; ++ni) accO[ni] = (floatx4){0.f, 0.f, 0.f, 0.f};

  __hip_bfloat16* Ps = QPs;

  const int ktmax = 2 * qt + 1;
  for (int kt = 0; kt <= ktmax; ++kt) {
    __syncthreads();
    const int ktok = b * SS + kt * 64;

    // stage K: 64 rows x 128 dims
#pragma unroll
    for (int i = 0; i < 2; ++i) {
      int c = tid + i * 512;
      int row = c >> 4;
      int dc  = (c & 15) * 8;
      short8 v = *(const short8*)(qkv + (size_t)(ktok + row) * QKVN + HIDDEN + h * HEADDIM + dc);
      *(short8*)(Ks + row * 136 + dc) = v;
    }
    // stage V transposed: Vt[d][k], 128 x 64 (stride 72)
#pragma unroll
    for (int i = 0; i < 4; ++i) {
      int c  = tid + i * 512;
      int dp = (c & 7) | ((c >> 3) & 0x38);
      int kp = ((c >> 3) & 7) | ((c >> 6) & 0x18);
      const __hip_bfloat16* g = qkv + (size_t)(ktok + 2 * kp) * QKVN + 2 * HIDDEN + h * HEADDIM + 2 * dp;
      __hip_bfloat162 v0 = *(const __hip_bfloat162*)g;
      __hip_bfloat162 v1 = *(const __hip_bfloat162*)(g + QKVN);
      __hip_bfloat162 w0, w1;
      w0.x = v0.x; w0.y = v1.x;
      w1.x = v0.y; w1.y = v1.y;
      *(__hip_bfloat162*)(Vt + (2 * dp) * 72 + 2 * kp)     = w0;
      *(__hip_bfloat162*)(Vt + (2 * dp + 1) * 72 + 2 * kp) = w1;
    }
    __syncthreads();

    // waves 0-3 (rows < 64) have an entirely-masked final tile: skip compute (wave-uniform)
    const bool active = !(wid < 4 && kt == ktmax);
    if (active) {
      floatx4 accS[4] = {};
#pragma unroll
      for (int ni = 0; ni < 4; ++ni)
#pragma unroll
        for (int kc = 0; kc < 4; ++kc) {
          short8 bk = *(const short8*)(Ks + (16 * ni + l16) * 136 + kc * 32 + quad * 8);
          accS[ni] = __builtin_amdgcn_mfma_f32_16x16x32_bf16(aq[kc], bk, accS[ni], 0, 0, 0);
        }

      float sv[4][4];
#pragma unroll
      for (int ni = 0; ni < 4; ++ni)
#pragma unroll
        for (int r = 0; r < 4; ++r) sv[ni][r] = accS[ni][r] * scale;
      if (kt >= 2 * qt) {   // diagonal zone: general causal mask
#pragma unroll
        for (int ni = 0; ni < 4; ++ni)
#pragma unroll
          for (int r = 0; r < 4; ++r)
            if (kt * 64 + 16 * ni + l16 > qt * 128 + wid * 16 + quad * 4 + r)
              sv[ni][r] = -INFINITY;
      }
#pragma unroll
      for (int r = 0; r < 4; ++r) {
        float mx = fmaxf(fmaxf(sv[0][r], sv[1][r]), fmaxf(sv[2][r], sv[3][r]));
        mx = fmaxf(mx, __shfl_xor(mx, 1));
        mx = fmaxf(mx, __shfl_xor(mx, 2));
        mx = fmaxf(mx, __shfl_xor(mx, 4));
        mx = fmaxf(mx, __shfl_xor(mx, 8));
        float mnew  = fmaxf(m_r[r], mx);
        float alpha = __expf(m_r[r] - mnew);
        float psum = 0.f;
#pragma unroll
        for (int ni = 0; ni < 4; ++ni) {
          float p = __expf(sv[ni][r] - mnew);
          psum += p;
          Ps[(wid * 16 + quad * 4 + r) * 72 + 16 * ni + l16] = __float2bfloat16(p);
        }
        psum += __shfl_xor(psum, 1);
        psum += __shfl_xor(psum, 2);
        psum += __shfl_xor(psum, 4);
        psum += __shfl_xor(psum, 8);
        l_r[r] = l_r[r] * alpha + psum;
        m_r[r] = mnew;
#pragma unroll
        for (int ni = 0; ni < 8; ++ni) accO[ni][r] *= alpha;
      }

      short8 ap[2];
#pragma unroll
      for (int kc = 0; kc < 2; ++kc)
        ap[kc] = *(const short8*)(Ps + (wid * 16 + l16) * 72 + kc * 32 + quad * 8);
#pragma unroll
      for (int ni = 0; ni < 8; ++ni)
#pragma unroll
        for (int kc = 0; kc < 2; ++kc) {
          short8 bv = *(const short8*)(Vt + (16 * ni + l16) * 72 + kc * 32 + quad * 8);
          accO[ni] = __builtin_amdgcn_mfma_f32_16x16x32_bf16(ap[kc], bv, accO[ni], 0, 0, 0);
        }
    }
  }

  float inv_l[4];
#pragma unroll
  for (int r = 0; r < 4; ++r) inv_l[r] = 1.0f / l_r[r];
#pragma unroll
  for (int ni = 0; ni < 8; ++ni)
#pragma unroll
    for (int r = 0; r < 4; ++r) {
      int row = qtok0 + wid * 16 + quad * 4 + r;
      int col = h * HEADDIM + 16 * ni + l16;
      out[(size_t)row * HIDDEN + col] = __float2bfloat16(accO[ni][r] * inv_l[r]);
    }
}

// ---------------- launch ----------------
extern "C" void kernel_launch(void* const* d_in, const int* in_sizes, int n_in,
                              void* d_out, int out_size, void* d_ws, size_t ws_size,
                              hipStream_t stream) {
  const float* hidden    = (const float*)d_in[0];
  const int*   positions = (const int*)d_in[1];
  const float* Wqkv      = (const float*)d_in[2];
  const float* Wout      = (const float*)d_in[3];
  float* out = (float*)d_out;

  const size_t R0_BYTES      = (size_t)NTOK * HIDDEN * 2;    // 33.55 MB: Xb, later Ab
  const size_t QKV_BYTES     = (size_t)NTOK * QKVN * 2;      // 100.66 MB
  const size_t WT_FULL_BYTES = (size_t)QKVN * HIDDEN * 2;    // 100.66 MB
  const size_t WT_CHUNK_BYTES= (size_t)HIDDEN * HIDDEN * 2;  // 33.55 MB

  const size_t WS_FULL  = R0_BYTES + WT_FULL_BYTES + QKV_BYTES;   // 234.9 MB
  const size_t WS_CHUNK = R0_BYTES + WT_CHUNK_BYTES + QKV_BYTES;  // 167.77 MB
  if (ws_size < WS_CHUNK) return;
  const bool full = (ws_size >= WS_FULL);

  char* ws = (char*)d_ws;
  __hip_bfloat16* Xb   = (__hip_bfloat16*)ws;                 // R0
  __hip_bfloat16* Ab   = (__hip_bfloat16*)ws;                 // R0 (aliases Xb, dead by then)
  __hip_bfloat16* Wt   = (__hip_bfloat16*)(ws + R0_BYTES);    // R1 (full or chunk)
  __hip_bfloat16* QKVb = (__hip_bfloat16*)(ws + R0_BYTES + (full ? WT_FULL_BYTES : WT_CHUNK_BYTES));

  // 1. cast hidden fp32 -> bf16
  cast_bf16_kernel<<<(NTOK * HIDDEN / 4 + 255) / 256, 256, 0, stream>>>(
      hidden, Xb, NTOK * HIDDEN / 4);

  // 2. QKV projection
  if (full) {
    transpose_cast_kernel<<<dim3(QKVN / 256, HIDDEN / 32), 256, 0, stream>>>(
        Wqkv, Wt, HIDDEN, QKVN, 0);
    gemm_bt256_kernel<__hip_bfloat16><<<dim3(QKVN / 256, NTOK / 256), 512, 0, stream>>>(
        Xb, Wt, QKVb, NTOK, HIDDEN, QKVN);
  } else {
    for (int p = 0; p < 3; ++p) {
      transpose_cast_kernel<<<dim3(HIDDEN / 256, HIDDEN / 32), 256, 0, stream>>>(
          Wqkv, Wt, HIDDEN, QKVN, p * HIDDEN);
      gemm_bt256_kernel<__hip_bfloat16><<<dim3(HIDDEN / 256, NTOK / 256), 512, 0, stream>>>(
          Xb, Wt, QKVb + p * HIDDEN, NTOK, HIDDEN, QKVN);
    }
  }

  // 3. RoPE on q,k
  rope_kernel<<<(NTOK * NHEADS * (ROT / 2) + 255) / 256, 256, 0, stream>>>(QKVb, positions);

  // 4. causal flash attention -> Ab (aliases Xb; Xb dead after gemm1)
  attn_kernel<<<BB * NHEADS * (SS / 128), 512, 0, stream>>>(QKVb, Ab);

  // 5. out projection (transpose Wout into Wt region — free after gemm1)
  transpose_cast_kernel<<<dim3(HIDDEN / 256, HIDDEN / 32), 256, 0, stream>>>(
      Wout, Wt, HIDDEN, HIDDEN, 0);
  gemm_bt256_kernel<float><<<dim3(HIDDEN / 256, NTOK / 256), 512, 0, stream>>>(
      Ab, Wt, out, NTOK, HIDDEN, HIDDEN);
}

// Round 4
// 1193.944 us; speedup vs baseline: 1.2476x; 1.0348x over previous
//
#include <hip/hip_runtime.h>
#include <hip/hip_bf16.h>
#include <stdint.h>

#define HIDDEN 4096
#define NHEADS 32
#define HEADDIM 128
#define ROT 64
#define BB 2
#define SS 2048
#define NTOK (BB*SS)        // 4096 tokens
#define QKVN (3*HIDDEN)     // 12288

typedef __attribute__((ext_vector_type(8))) short short8;
typedef __attribute__((ext_vector_type(4))) float floatx4;

#define WAITV(N) asm volatile("s_waitcnt vmcnt(" #N ")" ::: "memory")

__device__ __forceinline__ void barrier_raw() {
  asm volatile("" ::: "memory");
  __builtin_amdgcn_s_barrier();
  asm volatile("" ::: "memory");
}

// ---------------- async global->LDS 16B (wave-uniform LDS base + lane*16) ----------------
__device__ __forceinline__ void async16(const __hip_bfloat16* g, unsigned lds_byte_addr) {
  __builtin_amdgcn_global_load_lds(
      (const __attribute__((address_space(1))) unsigned int*)(uintptr_t)g,
      (__attribute__((address_space(3))) unsigned int*)(uintptr_t)(uint64_t)lds_byte_addr,
      16, 0, 0);
}

// ---------------- cast fp32 -> bf16 ----------------
__global__ void cast_bf16_kernel(const float* __restrict__ x,
                                 __hip_bfloat16* __restrict__ y, int n4) {
  int idx = blockIdx.x * blockDim.x + threadIdx.x;
  if (idx >= n4) return;
  float4 v = ((const float4*)x)[idx];
  __hip_bfloat162 a, b;
  a.x = __float2bfloat16(v.x); a.y = __float2bfloat16(v.y);
  b.x = __float2bfloat16(v.z); b.y = __float2bfloat16(v.w);
  ((__hip_bfloat162*)y)[idx * 2]     = a;
  ((__hip_bfloat162*)y)[idx * 2 + 1] = b;
}

// ---------------- transpose+cast: Wt[n][k] (bf16) = W[k][n_off+n] (fp32, row stride ldn) ----
__global__ void transpose_cast_kernel(const float* __restrict__ W,
                                      __hip_bfloat16* __restrict__ Wt,
                                      int K, int ldn, int n_off) {
  int n  = blockIdx.x * 256 + threadIdx.x;
  int k0 = blockIdx.y * 32;
  const float* src = W + (size_t)k0 * ldn + n_off + n;
  short8 outv[4];
#pragma unroll
  for (int i = 0; i < 4; ++i) {
#pragma unroll
    for (int j = 0; j < 8; ++j) {
      __hip_bfloat16 b = __float2bfloat16(src[(size_t)(i * 8 + j) * ldn]);
      outv[i][j] = *reinterpret_cast<short*>(&b);
    }
  }
  __hip_bfloat16* dst = Wt + (size_t)n * K + k0;
#pragma unroll
  for (int i = 0; i < 4; ++i) *(short8*)(dst + i * 8) = outv[i];
}

// ---------------- 256x256-tile MFMA GEMM, BK=32, fragment-order LDS ----------------
// C[M,n0..] = A[M][K] * Bt[N][K]^T.  8 waves (2Mx4N), per-wave 128x64 output.
// LDS layout (the R4 fix): per 32-k phase buffer, operand tile stored in FRAGMENT
// ORDER: [xblock 0..15][lane 0..63][8 bf16]. A fragment read is then
// base + xb*1024B + lane*16B  ->  contiguous wave64 1KB sweep = 0 bank conflicts
// by construction (R3 measured 4.0 conflict-cyc per ds_read_b128 in the k-major
// row layout, invariant under slot swizzles).
// global_load_lds writes linearly (lane*16), so the *global source lane-map* is
// permuted instead: lane covers row (lane&15), k-chunk (lane>>4)  (same address
// set as before -> identical coalescing/FETCH).
// Schedule: 3 buffers (96 KB), stage distance 2, ONE barrier per phase:
//   [ WAITV(4) ; barrier ; stage(p+2) ; 12 ds_read ; 32 MFMA ]
// vmcnt ledger: outstanding at WAITV = S(p)+S(p+1) = 8 -> WAITV(4) drains S(p).
__device__ inline void store_val(float* p, float v) { *p = v; }
__device__ inline void store_val(__hip_bfloat16* p, float v) { *p = __float2bfloat16(v); }

template <typename OutT>
__global__ __launch_bounds__(512) void gemm_bt256_kernel(const __hip_bfloat16* __restrict__ A,
                                                         const __hip_bfloat16* __restrict__ Bt,
                                                         OutT* __restrict__ C,
                                                         int M, int K, int ldc) {
  // [3 buf][16 xblock][64 lane][8 elems] = 24576 elems = 48 KB per operand
  __shared__ __align__(16) __hip_bfloat16 As[24576];
  __shared__ __align__(16) __hip_bfloat16 Bs[24576];

  const int tid  = threadIdx.x;
  const int wid  = tid >> 6;           // 0..7
  const int lane = tid & 63;
  const int quad = lane >> 4;
  const int l16  = lane & 15;
  const int wm   = (wid >> 2) * 128;   // wave row offset (2 M-halves)
  const int wn   = (wid & 3) * 64;     // wave col offset (4 N-quarters)

  // XCD-aware bijective swizzle (all launches have nwg % 8 == 0)
  const unsigned nwg = gridDim.x * gridDim.y;
  const unsigned wg  = blockIdx.y * gridDim.x + blockIdx.x;
  unsigned swz = wg;
  if ((nwg & 7u) == 0u) swz = (wg & 7u) * (nwg >> 3) + (wg >> 3);
  const int m0 = (int)(swz / gridDim.x) * 256;
  const int n0 = (int)(swz % gridDim.x) * 256;

  const unsigned asB = (unsigned)(uintptr_t)(&As[0]);
  const unsigned bsB = (unsigned)(uintptr_t)(&Bs[0]);

  // staging lane-map: lane covers row (lane&15) of its xblock, k-chunk (lane>>4)*8
  const __hip_bfloat16* pA = A  + ((size_t)(m0 + 2 * wid * 16 + (lane & 15))) * K + (lane >> 4) * 8;
  const __hip_bfloat16* pB = Bt + ((size_t)(n0 + 2 * wid * 16 + (lane & 15))) * K + (lane >> 4) * 8;
  const size_t xbskip = (size_t)16 * K;   // next xblock (16 rows)

  // wave wid stages A xblocks {2wid,2wid+1} and B xblocks {2wid,2wid+1}
  auto stage = [&](int p, int b3) {
    const int kb = p * 32;
    unsigned la = __builtin_amdgcn_readfirstlane(asB + (unsigned)(b3 * 16384 + wid * 2048));
    async16(pA + kb,          la);
    async16(pA + xbskip + kb, la + 1024);
    unsigned lb = __builtin_amdgcn_readfirstlane(bsB + (unsigned)(b3 * 16384 + wid * 2048));
    async16(pB + kb,          lb);
    async16(pB + xbskip + kb, lb + 1024);
  };

  const int NT = K >> 5;   // K/32 phases (K=4096 -> 128)
  floatx4 acc[8][4] = {};

  // fragment-read bases (elems): A xblocks (wid>>2)*8 + x ; B xblocks (wid&3)*4 + x
  const int aBase = ((wid >> 2) * 8) * 512 + lane * 8;
  const int bBase = ((wid & 3) * 4) * 512 + lane * 8;

  stage(0, 0);
  stage(1, 1);

  int pb = 0, sb = 2;
  for (int p = 0; p < NT; ++p) {
    if (p + 1 < NT) { WAITV(4); } else { WAITV(0); }
    barrier_raw();
    if (p + 2 < NT) { stage(p + 2, sb); sb = (sb == 2) ? 0 : sb + 1; }

    const int bufE = pb * 8192;
    short8 af[8], bf[4];
#pragma unroll
    for (int x = 0; x < 8; ++x)
      af[x] = *(const short8*)(As + bufE + aBase + x * 512);
#pragma unroll
    for (int x = 0; x < 4; ++x)
      bf[x] = *(const short8*)(Bs + bufE + bBase + x * 512);

    __builtin_amdgcn_s_setprio(1);
#pragma unroll
    for (int mi = 0; mi < 8; ++mi)
#pragma unroll
      for (int ni = 0; ni < 4; ++ni)
        acc[mi][ni] = __builtin_amdgcn_mfma_f32_16x16x32_bf16(af[mi], bf[ni], acc[mi][ni], 0, 0, 0);
    __builtin_amdgcn_s_setprio(0);

    pb = (pb == 2) ? 0 : pb + 1;
  }

  // epilogue: C/D layout row=quad*4+r, col=lane&15 (verified m89/m91)
#pragma unroll
  for (int mi = 0; mi < 8; ++mi)
#pragma unroll
    for (int ni = 0; ni < 4; ++ni)
#pragma unroll
      for (int r = 0; r < 4; ++r) {
        int row = m0 + wm + mi * 16 + quad * 4 + r;
        int col = n0 + wn + ni * 16 + l16;
        store_val(C + (size_t)row * ldc + col, acc[mi][ni][r]);
      }
}

// ---------------- RoPE (NeoX), in place on q and k halves of qkv ----------------
__global__ void rope_kernel(__hip_bfloat16* __restrict__ qkv,
                            const int* __restrict__ positions) {
  int idx = blockIdx.x * blockDim.x + threadIdx.x;
  if (idx >= NTOK * NHEADS * (ROT / 2)) return;
  int i   = idx & 31;
  int h   = (idx >> 5) & 31;
  int tok = idx >> 10;
  float pos = (float)positions[tok];
  float inv_freq = __expf(-(float)i * 0.28782313662425574f);
  float ang = pos * inv_freq;
  float sv, cv;
  sincosf(ang, &sv, &cv);
  size_t base = (size_t)tok * QKVN + h * HEADDIM + i;
  {
    float x1 = __bfloat162float(qkv[base]);
    float x2 = __bfloat162float(qkv[base + 32]);
    qkv[base]      = __float2bfloat16(x1 * cv - x2 * sv);
    qkv[base + 32] = __float2bfloat16(x2 * cv + x1 * sv);
  }
  {
    float x1 = __bfloat162float(qkv[base + HIDDEN]);
    float x2 = __bfloat162float(qkv[base + HIDDEN + 32]);
    qkv[base + HIDDEN]      = __float2bfloat16(x1 * cv - x2 * sv);
    qkv[base + HIDDEN + 32] = __float2bfloat16(x2 * cv + x1 * sv);
  }
}

// ---------------- MFMA flash attention: QBLK=128, 8 waves, KVBLK=64 ----------------
// R4: K and V tiles in fragment-order LDS (contiguous ds_write_b128 staging,
// contiguous wave64 bk/bv reads -> conflict-free).
__global__ __launch_bounds__(512) void attn_kernel(const __hip_bfloat16* __restrict__ qkv,
                                                   __hip_bfloat16* __restrict__ out) {
  __shared__ __hip_bfloat16 QPs[128 * 136];   // Q tile; later aliased as P (stride 72)
  __shared__ __align__(16) __hip_bfloat16 Kf[8192];  // [4 ni][4 kc][64 lane][8]
  __shared__ __align__(16) __hip_bfloat16 Vf[8192];  // [8 ni][2 kc][64 lane][8]

  const int tid  = threadIdx.x;
  const int wid  = tid >> 6;          // 0..7
  const int lane = tid & 63;
  const int quad = lane >> 4;
  const int l16  = lane & 15;
  const int qt   = 15 - (blockIdx.x & 15);      // descending work: big blocks first
  const int h    = (blockIdx.x >> 4) & 31;
  const int b    = blockIdx.x >> 9;
  const int qtok0 = b * SS + qt * 128;
  const float scale = 0.08838834764831843f;

  // stage Q: 128 rows x 128 dims
#pragma unroll
  for (int i = 0; i < 4; ++i) {
    int c = tid + i * 512;
    int row = c >> 4;
    int dc  = (c & 15) * 8;
    short8 v = *(const short8*)(qkv + (size_t)(qtok0 + row) * QKVN + h * HEADDIM + dc);
    *(short8*)(QPs + row * 136 + dc) = v;
  }
  __syncthreads();
  short8 aq[4];
#pragma unroll
  for (int kc = 0; kc < 4; ++kc)
    aq[kc] = *(const short8*)(QPs + (wid * 16 + l16) * 136 + kc * 32 + quad * 8);

  float m_r[4], l_r[4];
  floatx4 accO[8];
#pragma unroll
  for (int r = 0; r < 4; ++r) { m_r[r] = -INFINITY; l_r[r] = 0.f; }
#pragma unroll
  for (int ni = 0; ni < 8; ++ni) accO[ni] = (floatx4){0.f, 0.f, 0.f, 0.f};

  __hip_bfloat16* Ps = QPs;

  const int ktmax = 2 * qt + 1;
  for (int kt = 0; kt <= ktmax; ++kt) {
    __syncthreads();
    const int ktok = b * SS + kt * 64;

    // stage K fragment-order: chunk L -> kv row ((L>>8)&3)*16 + (L&15),
    // k-col ((L>>6)&3)*32 + ((L>>4)&3)*8. ds_write_b128 contiguous per wave.
#pragma unroll
    for (int i = 0; i < 2; ++i) {
      int L = tid + i * 512;
      int row = ((L >> 8) & 3) * 16 + (L & 15);
      int col = ((L >> 6) & 3) * 32 + ((L >> 4) & 3) * 8;
      short8 v = *(const short8*)(qkv + (size_t)(ktok + row) * QKVN + HIDDEN + h * HEADDIM + col);
      *(short8*)(Kf + L * 8) = v;
    }
    // stage V fragment-order (transposed): chunk L holds d = (L>>7)*16 + (L&15),
    // kv = ((L>>6)&1)*32 + ((L>>4)&3)*8 .. +7. Thread handles L=2*tid, 2*tid+1
    // (d pair), gathering 8 bf16x2 rows and packing lows/highs.
    {
      int L  = tid * 2;
      int d0  = ((L >> 7) & 7) * 16 + (L & 15);
      int kv0 = ((L >> 6) & 1) * 32 + ((L >> 4) & 3) * 8;
      const __hip_bfloat16* g = qkv + (size_t)(ktok + kv0) * QKVN + 2 * HIDDEN + h * HEADDIM + d0;
      short8 w0, w1;
#pragma unroll
      for (int j = 0; j < 8; ++j) {
        __hip_bfloat162 vv = *(const __hip_bfloat162*)(g + (size_t)j * QKVN);
        w0[j] = *reinterpret_cast<const short*>(&vv.x);
        w1[j] = *reinterpret_cast<const short*>(&vv.y);
      }
      *(short8*)(Vf + L * 8)     = w0;
      *(short8*)(Vf + L * 8 + 8) = w1;
    }
    __syncthreads();

    // waves 0-3 (rows < 64) have an entirely-masked final tile: skip compute (wave-uniform)
    const bool active = !(wid < 4 && kt == ktmax);
    if (active) {
      floatx4 accS[4] = {};
#pragma unroll
      for (int ni = 0; ni < 4; ++ni)
#pragma unroll
        for (int kc = 0; kc < 4; ++kc) {
          short8 bk = *(const short8*)(Kf + ni * 2048 + kc * 512 + lane * 8);
          accS[ni] = __builtin_amdgcn_mfma_f32_16x16x32_bf16(aq[kc], bk, accS[ni], 0, 0, 0);
        }

      float sv[4][4];
#pragma unroll
      for (int ni = 0; ni < 4; ++ni)
#pragma unroll
        for (int r = 0; r < 4; ++r) sv[ni][r] = accS[ni][r] * scale;
      if (kt >= 2 * qt) {   // diagonal zone: general causal mask
#pragma unroll
        for (int ni = 0; ni < 4; ++ni)
#pragma unroll
          for (int r = 0; r < 4; ++r)
            if (kt * 64 + 16 * ni + l16 > qt * 128 + wid * 16 + quad * 4 + r)
              sv[ni][r] = -INFINITY;
      }
#pragma unroll
      for (int r = 0; r < 4; ++r) {
        float mx = fmaxf(fmaxf(sv[0][r], sv[1][r]), fmaxf(sv[2][r], sv[3][r]));
        mx = fmaxf(mx, __shfl_xor(mx, 1));
        mx = fmaxf(mx, __shfl_xor(mx, 2));
        mx = fmaxf(mx, __shfl_xor(mx, 4));
        mx = fmaxf(mx, __shfl_xor(mx, 8));
        float mnew  = fmaxf(m_r[r], mx);
        float alpha = __expf(m_r[r] - mnew);
        float psum = 0.f;
#pragma unroll
        for (int ni = 0; ni < 4; ++ni) {
          float p = __expf(sv[ni][r] - mnew);
          psum += p;
          Ps[(wid * 16 + quad * 4 + r) * 72 + 16 * ni + l16] = __float2bfloat16(p);
        }
        psum += __shfl_xor(psum, 1);
        psum += __shfl_xor(psum, 2);
        psum += __shfl_xor(psum, 4);
        psum += __shfl_xor(psum, 8);
        l_r[r] = l_r[r] * alpha + psum;
        m_r[r] = mnew;
#pragma unroll
        for (int ni = 0; ni < 8; ++ni) accO[ni][r] *= alpha;
      }

      short8 ap[2];
#pragma unroll
      for (int kc = 0; kc < 2; ++kc)
        ap[kc] = *(const short8*)(Ps + (wid * 16 + l16) * 72 + kc * 32 + quad * 8);
#pragma unroll
      for (int ni = 0; ni < 8; ++ni)
#pragma unroll
        for (int kc = 0; kc < 2; ++kc) {
          short8 bv = *(const short8*)(Vf + ni * 1024 + kc * 512 + lane * 8);
          accO[ni] = __builtin_amdgcn_mfma_f32_16x16x32_bf16(ap[kc], bv, accO[ni], 0, 0, 0);
        }
    }
  }

  float inv_l[4];
#pragma unroll
  for (int r = 0; r < 4; ++r) inv_l[r] = 1.0f / l_r[r];
#pragma unroll
  for (int ni = 0; ni < 8; ++ni)
#pragma unroll
    for (int r = 0; r < 4; ++r) {
      int row = qtok0 + wid * 16 + quad * 4 + r;
      int col = h * HEADDIM + 16 * ni + l16;
      out[(size_t)row * HIDDEN + col] = __float2bfloat16(accO[ni][r] * inv_l[r]);
    }
}

// ---------------- launch ----------------
extern "C" void kernel_launch(void* const* d_in, const int* in_sizes, int n_in,
                              void* d_out, int out_size, void* d_ws, size_t ws_size,
                              hipStream_t stream) {
  const float* hidden    = (const float*)d_in[0];
  const int*   positions = (const int*)d_in[1];
  const float* Wqkv      = (const float*)d_in[2];
  const float* Wout      = (const float*)d_in[3];
  float* out = (float*)d_out;

  const size_t R0_BYTES      = (size_t)NTOK * HIDDEN * 2;    // 33.55 MB: Xb, later Ab
  const size_t QKV_BYTES     = (size_t)NTOK * QKVN * 2;      // 100.66 MB
  const size_t WT_FULL_BYTES = (size_t)QKVN * HIDDEN * 2;    // 100.66 MB
  const size_t WT_CHUNK_BYTES= (size_t)HIDDEN * HIDDEN * 2;  // 33.55 MB

  const size_t WS_FULL  = R0_BYTES + WT_FULL_BYTES + QKV_BYTES;   // 234.9 MB
  const size_t WS_CHUNK = R0_BYTES + WT_CHUNK_BYTES + QKV_BYTES;  // 167.77 MB
  if (ws_size < WS_CHUNK) return;
  const bool full = (ws_size >= WS_FULL);

  char* ws = (char*)d_ws;
  __hip_bfloat16* Xb   = (__hip_bfloat16*)ws;                 // R0
  __hip_bfloat16* Ab   = (__hip_bfloat16*)ws;                 // R0 (aliases Xb, dead by then)
  __hip_bfloat16* Wt   = (__hip_bfloat16*)(ws + R0_BYTES);    // R1 (full or chunk)
  __hip_bfloat16* QKVb = (__hip_bfloat16*)(ws + R0_BYTES + (full ? WT_FULL_BYTES : WT_CHUNK_BYTES));

  // 1. cast hidden fp32 -> bf16
  cast_bf16_kernel<<<(NTOK * HIDDEN / 4 + 255) / 256, 256, 0, stream>>>(
      hidden, Xb, NTOK * HIDDEN / 4);

  // 2. QKV projection
  if (full) {
    transpose_cast_kernel<<<dim3(QKVN / 256, HIDDEN / 32), 256, 0, stream>>>(
        Wqkv, Wt, HIDDEN, QKVN, 0);
    gemm_bt256_kernel<__hip_bfloat16><<<dim3(QKVN / 256, NTOK / 256), 512, 0, stream>>>(
        Xb, Wt, QKVb, NTOK, HIDDEN, QKVN);
  } else {
    for (int p = 0; p < 3; ++p) {
      transpose_cast_kernel<<<dim3(HIDDEN / 256, HIDDEN / 32), 256, 0, stream>>>(
          Wqkv, Wt, HIDDEN, QKVN, p * HIDDEN);
      gemm_bt256_kernel<__hip_bfloat16><<<dim3(HIDDEN / 256, NTOK / 256), 512, 0, stream>>>(
          Xb, Wt, QKVb + p * HIDDEN, NTOK, HIDDEN, QKVN);
    }
  }

  // 3. RoPE on q,k
  rope_kernel<<<(NTOK * NHEADS * (ROT / 2) + 255) / 256, 256, 0, stream>>>(QKVb, positions);

  // 4. causal flash attention -> Ab (aliases Xb; Xb dead after gemm1)
  attn_kernel<<<BB * NHEADS * (SS / 128), 512, 0, stream>>>(QKVb, Ab);

  // 5. out projection (transpose Wout into Wt region — free after gemm1)
  transpose_cast_kernel<<<dim3(HIDDEN / 256, HIDDEN / 32), 256, 0, stream>>>(
      Wout, Wt, HIDDEN, HIDDEN, 0);
  gemm_bt256_kernel<float><<<dim3(HIDDEN / 256, NTOK / 256), 512, 0, stream>>>(
      Ab, Wt, out, NTOK, HIDDEN, HIDDEN);
}